// Round 4
// baseline (545.137 us; speedup 1.0000x reference)
//
#include <hip/hip_runtime.h>
#include <hip/hip_bf16.h>
#include <stdint.h>

// Problem constants (fixed by the reference)
#define N_EDGES   800000
#define N_NODESC  50000
#define HID       128

typedef __attribute__((ext_vector_type(8))) short bf16x8;  // 8 bf16 = 4 VGPRs (MFMA A/B frag)
typedef __attribute__((ext_vector_type(4))) float f32x4;   // MFMA C/D frag
typedef __attribute__((ext_vector_type(4))) unsigned int u32x4;

__device__ __forceinline__ short f2bf(float f) {
    union { float f; uint32_t u; } v; v.f = f;
    uint32_t r = v.u + 0x7FFFu + ((v.u >> 16) & 1u);   // round-to-nearest-even
    return (short)(r >> 16);
}

// pack two f32 -> bf16x2 (RNE) via native v_cvt_pk_bf16_f32 on gfx950
__device__ __forceinline__ uint32_t packbf2(float lo, float hi) {
    float2 t; t.x = lo; t.y = hi;
    __hip_bfloat162 h = __float22bfloat162_rn(t);
    uint32_t u;
    __builtin_memcpy(&u, &h, 4);       // __hip_bfloat162 not trivially copyable -> memcpy pun
    return u;
}

// packed bf16x2: (a + b) then relu.  Unpack is exact (shift/mask); f32 add then one
// RNE pack = single rounding, identical error bound to f32-add-then-round.
__device__ __forceinline__ uint32_t addrelu2(uint32_t a, uint32_t b) {
    union { uint32_t u; float f; } alo, ahi, blo, bhi;
    alo.u = a << 16;  ahi.u = a & 0xFFFF0000u;
    blo.u = b << 16;  bhi.u = b & 0xFFFF0000u;
    float slo = alo.f + blo.f;  slo = slo > 0.f ? slo : 0.f;
    float shi = ahi.f + bhi.f;  shi = shi > 0.f ? shi : 0.f;
    return packbf2(slo, shi);
}
__device__ __forceinline__ bf16x8 addrelu8(u32x4 p, u32x4 q) {
    u32x4 r;
    #pragma unroll
    for (int j = 0; j < 4; ++j) r[j] = addrelu2(p[j], q[j]);
    bf16x8 out;
    __builtin_memcpy(&out, &r, 16);
    return out;
}

// ---------------- workspace layout ----------------
// PQ  : bf16 [50000][1024]  (cols 0..511 = emb@W1_top + b1 "P'", 512..1023 = emb@W1_bot "Q")
// W1s : bf16 frag-major, 4*64 frags x 64 lanes x 8   (B-frags of W1cat [128,1024])
// W2s : bf16 frag-major, 16*8 frags x 64 lanes x 8   (B-frags of W2 [512,128])
#define PQ_OFF   0UL
#define W1S_OFF  102400000UL                 // 50000*1024*2
#define W2S_OFF  (W1S_OFF + 262144UL)        // + 128*1024*2
// total ws needed: 102,793,216 bytes

// ============ kernel 0: weight convert + B-fragment swizzle ============
// B-frag for 16x16x32 bf16: lane l holds B[k = kc*32 + (l>>4)*8 + j][n = nt*16 + (l&15)], j=0..7
__global__ __launch_bounds__(256) void swizzle_kernel(const float* __restrict__ W1,
                                                      const float* __restrict__ W2,
                                                      short* __restrict__ W1s,
                                                      short* __restrict__ W2s) {
    int t = blockIdx.x * 256 + threadIdx.x;
    int lane = t & 63;
    int kq = lane >> 4;       // 0..3
    int nn = lane & 15;
    if (t < 16384) {          // W1cat: K=128, N=1024 -> kc 0..3, nt 0..63
        int frag = t >> 6;
        int kc = frag >> 6;
        int nt = frag & 63;
        int n = nt * 16 + nn;
        int kbase = kc * 32 + kq * 8;
        bf16x8 v;
        #pragma unroll
        for (int j = 0; j < 8; ++j) {
            int k = kbase + j;
            float f = (n < 512) ? W1[k * 512 + n] : W1[(128 + k) * 512 + (n - 512)];
            v[j] = f2bf(f);
        }
        *(bf16x8*)(W1s + frag * 512 + lane * 8) = v;
    } else if (t < 24576) {   // W2: K=512, N=128 -> kc 0..15, nt 0..7
        int t2 = t - 16384;
        int frag = t2 >> 6;
        int kc = frag >> 3;
        int nt = frag & 7;
        int n = nt * 16 + nn;
        int kbase = kc * 32 + kq * 8;
        bf16x8 v;
        #pragma unroll
        for (int j = 0; j < 8; ++j) v[j] = f2bf(W2[(kbase + j) * HID + n]);
        *(bf16x8*)(W2s + frag * 512 + lane * 8) = v;
    }
}

// ============ kernel 1: PQ = emb @ W1cat (+b1 on P half) — LDS-free, 2 m-tiles/wave ============
// grid 1563 x 256: block = 32 node rows, 4 waves each owning 256 of 1024 cols.
// B-frags shared across the 2 m-tiles -> W1s L2 traffic halved vs R2.
__global__ __launch_bounds__(256) void precompute_kernel(const float* __restrict__ emb,
                                                         const short* __restrict__ W1s,
                                                         const float* __restrict__ b1,
                                                         short* __restrict__ PQ) {
    int lane = threadIdx.x & 63;
    int w = threadIdx.x >> 6;
    int nb = blockIdx.x * 32;
    int m = lane & 15;
    int kq = lane >> 4;

    int n0 = nb + m;       if (n0 > N_NODESC - 1) n0 = N_NODESC - 1;   // clamp OOB loads
    int n1 = nb + 16 + m;  if (n1 > N_NODESC - 1) n1 = N_NODESC - 1;
    const float* a0p = emb + (size_t)n0 * 128 + kq * 8;
    const float* a1p = emb + (size_t)n1 * 128 + kq * 8;

    f32x4 acc[2][16];
    #pragma unroll
    for (int mt = 0; mt < 2; ++mt)
        #pragma unroll
        for (int i = 0; i < 16; ++i) acc[mt][i] = (f32x4){0.f, 0.f, 0.f, 0.f};

    #pragma unroll
    for (int kc = 0; kc < 4; ++kc) {
        f32x4 x0 = *(const f32x4*)(a0p + kc * 32);
        f32x4 x1 = *(const f32x4*)(a0p + kc * 32 + 4);
        f32x4 y0 = *(const f32x4*)(a1p + kc * 32);
        f32x4 y1 = *(const f32x4*)(a1p + kc * 32 + 4);
        u32x4 au, bu;
        au[0] = packbf2(x0[0], x0[1]); au[1] = packbf2(x0[2], x0[3]);
        au[2] = packbf2(x1[0], x1[1]); au[3] = packbf2(x1[2], x1[3]);
        bu[0] = packbf2(y0[0], y0[1]); bu[1] = packbf2(y0[2], y0[3]);
        bu[2] = packbf2(y1[0], y1[1]); bu[3] = packbf2(y1[2], y1[3]);
        bf16x8 a0, a1;
        __builtin_memcpy(&a0, &au, 16);
        __builtin_memcpy(&a1, &bu, 16);
        #pragma unroll
        for (int nt = 0; nt < 16; ++nt) {
            int frag = kc * 64 + (w * 16 + nt);
            bf16x8 b = *(const bf16x8*)(W1s + frag * 512 + lane * 8);
            acc[0][nt] = __builtin_amdgcn_mfma_f32_16x16x32_bf16(a0, b, acc[0][nt], 0, 0, 0);
            acc[1][nt] = __builtin_amdgcn_mfma_f32_16x16x32_bf16(a1, b, acc[1][nt], 0, 0, 0);
        }
    }

    // C/D layout: col = lane&15, row = (lane>>4)*4 + r.  Fold b1 into the P half (n<512).
    #pragma unroll
    for (int nt = 0; nt < 16; ++nt) {
        int n = w * 256 + nt * 16 + m;
        float bias = (n < 512) ? b1[n] : 0.0f;
        #pragma unroll
        for (int mt = 0; mt < 2; ++mt) {
            #pragma unroll
            for (int r = 0; r < 4; ++r) {
                int node = nb + mt * 16 + kq * 4 + r;
                if (node < N_NODESC)
                    PQ[(size_t)node * 1024 + n] = f2bf(acc[mt][nt][r] + bias);
            }
        }
    }
}

// ============ kernel 2: per-edge fused layer1(gather+add+relu) + layer2(MFMA) + layer3 ============
// grid 6250 x 256: each wave owns 32 edges as 2 m-tiles.  32 edges/wave @ 3 waves/SIMD
// (acc = 64 AGPR) trades W2 re-reads (3.2 GB, < L2 ceiling) for +50% latency-hiding streams.
// Full kc unroll: gathers become base+immediate, compiler software-pipelines under reg cap.
__global__ __launch_bounds__(256, 3) void edge_kernel(const short* __restrict__ PQ,
                                                      const int* __restrict__ ei,
                                                      const short* __restrict__ W2s,
                                                      const float* __restrict__ b2,
                                                      const float* __restrict__ W3,
                                                      const float* __restrict__ b3,
                                                      float* __restrict__ out) {
    int lane = threadIdx.x & 63;
    int w = threadIdx.x >> 6;
    int e0 = blockIdx.x * 128 + w * 32;
    int m = lane & 15;
    int kq = lane >> 4;

    // lanes 0..31: col idx of edges e0..e0+31; lanes 32..63: row idx of same edges
    int ii = (lane < 32) ? ei[e0 + lane] : ei[N_EDGES + e0 + (lane - 32)];

    int c0 = __shfl(ii, m, 64);
    int c1 = __shfl(ii, 16 + m, 64);
    int r0 = __shfl(ii, 32 + m, 64);
    int r1 = __shfl(ii, 48 + m, 64);
    const short* pb0 = PQ + (size_t)c0 * 1024 + kq * 8;         // P' half
    const short* pb1 = PQ + (size_t)c1 * 1024 + kq * 8;
    const short* qb0 = PQ + (size_t)r0 * 1024 + 512 + kq * 8;   // Q half
    const short* qb1 = PQ + (size_t)r1 * 1024 + 512 + kq * 8;

    f32x4 acc[2][8];
    #pragma unroll
    for (int t = 0; t < 2; ++t)
        #pragma unroll
        for (int nt = 0; nt < 8; ++nt) acc[t][nt] = (f32x4){0.f, 0.f, 0.f, 0.f};

    #pragma unroll
    for (int kc = 0; kc < 16; ++kc) {
        u32x4 p0 = *(const u32x4*)(pb0 + kc * 32);
        u32x4 q0 = *(const u32x4*)(qb0 + kc * 32);
        u32x4 p1 = *(const u32x4*)(pb1 + kc * 32);
        u32x4 q1 = *(const u32x4*)(qb1 + kc * 32);
        bf16x8 b[8];
        #pragma unroll
        for (int nt = 0; nt < 8; ++nt)
            b[nt] = *(const bf16x8*)(W2s + (kc * 8 + nt) * 512 + lane * 8);
        bf16x8 a0 = addrelu8(p0, q0);
        bf16x8 a1 = addrelu8(p1, q1);
        #pragma unroll
        for (int nt = 0; nt < 8; ++nt) {
            acc[0][nt] = __builtin_amdgcn_mfma_f32_16x16x32_bf16(a0, b[nt], acc[0][nt], 0, 0, 0);
            acc[1][nt] = __builtin_amdgcn_mfma_f32_16x16x32_bf16(a1, b[nt], acc[1][nt], 0, 0, 0);
        }
    }

    // ---- epilogue: +b2, relu, dot with W3, +b3 (all f32) ----
    float b2v[8], w3v[8];
    #pragma unroll
    for (int nt = 0; nt < 8; ++nt) {
        b2v[nt] = b2[nt * 16 + m];
        w3v[nt] = W3[nt * 16 + m];
    }
    float b3s = b3[0];
    #pragma unroll
    for (int t = 0; t < 2; ++t) {
        float partial[4] = {0.f, 0.f, 0.f, 0.f};
        #pragma unroll
        for (int nt = 0; nt < 8; ++nt) {
            #pragma unroll
            for (int r = 0; r < 4; ++r) {
                float x2 = acc[t][nt][r] + b2v[nt];       // C row = kq*4+r, col = nt*16+m
                x2 = x2 > 0.f ? x2 : 0.f;
                partial[r] += x2 * w3v[nt];
            }
        }
        #pragma unroll
        for (int r = 0; r < 4; ++r) {
            #pragma unroll
            for (int off = 1; off < 16; off <<= 1)
                partial[r] += __shfl_xor(partial[r], off, 64);
            if (m == 0) out[e0 + t * 16 + kq * 4 + r] = partial[r] + b3s;
        }
    }
}

extern "C" void kernel_launch(void* const* d_in, const int* in_sizes, int n_in,
                              void* d_out, int out_size, void* d_ws, size_t ws_size,
                              hipStream_t stream) {
    const float* emb = (const float*)d_in[0];
    const int*   ei  = (const int*)d_in[1];
    const float* W1  = (const float*)d_in[2];
    const float* b1  = (const float*)d_in[3];
    const float* W2  = (const float*)d_in[4];
    const float* b2  = (const float*)d_in[5];
    const float* W3  = (const float*)d_in[6];
    const float* b3  = (const float*)d_in[7];
    float* out = (float*)d_out;

    short* PQ  = (short*)((char*)d_ws + PQ_OFF);
    short* W1s = (short*)((char*)d_ws + W1S_OFF);
    short* W2s = (short*)((char*)d_ws + W2S_OFF);

    swizzle_kernel<<<96, 256, 0, stream>>>(W1, W2, W1s, W2s);
    precompute_kernel<<<(N_NODESC + 31) / 32, 256, 0, stream>>>(emb, W1s, b1, PQ);     // 1563 blocks
    edge_kernel<<<N_EDGES / 128, 256, 0, stream>>>(PQ, ei, W2s, b2, W3, b3, out);      // 6250 blocks
}

// Round 5
// 475.472 us; speedup vs baseline: 1.1465x; 1.1465x over previous
//
#include <hip/hip_runtime.h>
#include <hip/hip_bf16.h>
#include <stdint.h>

// Problem constants (fixed by the reference)
#define N_EDGES   800000
#define N_NODESC  50000
#define HID       128

typedef __attribute__((ext_vector_type(8))) short bf16x8;  // 8 bf16 = 4 VGPRs (MFMA A/B frag)
typedef __attribute__((ext_vector_type(4))) float f32x4;   // MFMA C/D frag
typedef __attribute__((ext_vector_type(4))) unsigned int u32x4;

__device__ __forceinline__ short f2bf(float f) {
    union { float f; uint32_t u; } v; v.f = f;
    uint32_t r = v.u + 0x7FFFu + ((v.u >> 16) & 1u);   // round-to-nearest-even
    return (short)(r >> 16);
}

// pack two f32 -> bf16x2 (RNE) via native v_cvt_pk_bf16_f32 on gfx950
__device__ __forceinline__ uint32_t packbf2(float lo, float hi) {
    float2 t; t.x = lo; t.y = hi;
    __hip_bfloat162 h = __float22bfloat162_rn(t);
    uint32_t u;
    __builtin_memcpy(&u, &h, 4);       // __hip_bfloat162 not trivially copyable -> memcpy pun
    return u;
}

// packed bf16x2 (a+b) then relu:
//   __hadd2 -> native v_pk_add_bf16 (one RNE rounding: bf16+bf16 is exact in f32,
//   rounded once — identical error to the f32-add-then-round path)
//   relu: integer sign-mask, exact.  ~5 VALU per 2 elements.
__device__ __forceinline__ uint32_t addrelu2(uint32_t a, uint32_t b) {
    __hip_bfloat162 ha, hb;
    __builtin_memcpy(&ha, &a, 4);
    __builtin_memcpy(&hb, &b, 4);
    __hip_bfloat162 s = __hadd2(ha, hb);
    uint32_t x;
    __builtin_memcpy(&x, &s, 4);
    uint32_t neg = (x & 0x80008000u) >> 15;      // 1 at bit0/bit16 where half negative
    return x & ~(neg * 0xFFFFu);                 // zero negative halves
}
__device__ __forceinline__ bf16x8 addrelu8(u32x4 p, u32x4 q) {
    u32x4 r;
    #pragma unroll
    for (int j = 0; j < 4; ++j) r[j] = addrelu2(p[j], q[j]);
    bf16x8 out;
    __builtin_memcpy(&out, &r, 16);
    return out;
}

// ---------------- workspace layout ----------------
// PQ  : bf16 [50000][1024]  (cols 0..511 = emb@W1_top + b1 "P'", 512..1023 = emb@W1_bot "Q")
// W1s : bf16 frag-major, 4*64 frags x 64 lanes x 8   (B-frags of W1cat [128,1024])
// W2s : bf16 frag-major, 16*8 frags x 64 lanes x 8   (B-frags of W2 [512,128])
#define PQ_OFF   0UL
#define W1S_OFF  102400000UL                 // 50000*1024*2
#define W2S_OFF  (W1S_OFF + 262144UL)        // + 128*1024*2
// total ws needed: 102,793,216 bytes

// ============ kernel 0: weight convert + B-fragment swizzle ============
// B-frag for 16x16x32 bf16: lane l holds B[k = kc*32 + (l>>4)*8 + j][n = nt*16 + (l&15)], j=0..7
__global__ __launch_bounds__(256) void swizzle_kernel(const float* __restrict__ W1,
                                                      const float* __restrict__ W2,
                                                      short* __restrict__ W1s,
                                                      short* __restrict__ W2s) {
    int t = blockIdx.x * 256 + threadIdx.x;
    int lane = t & 63;
    int kq = lane >> 4;       // 0..3
    int nn = lane & 15;
    if (t < 16384) {          // W1cat: K=128, N=1024 -> kc 0..3, nt 0..63
        int frag = t >> 6;
        int kc = frag >> 6;
        int nt = frag & 63;
        int n = nt * 16 + nn;
        int kbase = kc * 32 + kq * 8;
        bf16x8 v;
        #pragma unroll
        for (int j = 0; j < 8; ++j) {
            int k = kbase + j;
            float f = (n < 512) ? W1[k * 512 + n] : W1[(128 + k) * 512 + (n - 512)];
            v[j] = f2bf(f);
        }
        *(bf16x8*)(W1s + frag * 512 + lane * 8) = v;
    } else if (t < 24576) {   // W2: K=512, N=128 -> kc 0..15, nt 0..7
        int t2 = t - 16384;
        int frag = t2 >> 6;
        int kc = frag >> 3;
        int nt = frag & 7;
        int n = nt * 16 + nn;
        int kbase = kc * 32 + kq * 8;
        bf16x8 v;
        #pragma unroll
        for (int j = 0; j < 8; ++j) v[j] = f2bf(W2[(kbase + j) * HID + n]);
        *(bf16x8*)(W2s + frag * 512 + lane * 8) = v;
    }
}

// ============ kernel 1: PQ = emb @ W1cat (+b1 on P half) — LDS-free, 2 m-tiles/wave ============
// grid 1563 x 256: block = 32 node rows, 4 waves each owning 256 of 1024 cols.
__global__ __launch_bounds__(256) void precompute_kernel(const float* __restrict__ emb,
                                                         const short* __restrict__ W1s,
                                                         const float* __restrict__ b1,
                                                         short* __restrict__ PQ) {
    int lane = threadIdx.x & 63;
    int w = threadIdx.x >> 6;
    int nb = blockIdx.x * 32;
    int m = lane & 15;
    int kq = lane >> 4;

    int n0 = nb + m;       if (n0 > N_NODESC - 1) n0 = N_NODESC - 1;   // clamp OOB loads
    int n1 = nb + 16 + m;  if (n1 > N_NODESC - 1) n1 = N_NODESC - 1;
    const float* a0p = emb + (size_t)n0 * 128 + kq * 8;
    const float* a1p = emb + (size_t)n1 * 128 + kq * 8;

    f32x4 acc[2][16];
    #pragma unroll
    for (int mt = 0; mt < 2; ++mt)
        #pragma unroll
        for (int i = 0; i < 16; ++i) acc[mt][i] = (f32x4){0.f, 0.f, 0.f, 0.f};

    #pragma unroll
    for (int kc = 0; kc < 4; ++kc) {
        f32x4 x0 = *(const f32x4*)(a0p + kc * 32);
        f32x4 x1 = *(const f32x4*)(a0p + kc * 32 + 4);
        f32x4 y0 = *(const f32x4*)(a1p + kc * 32);
        f32x4 y1 = *(const f32x4*)(a1p + kc * 32 + 4);
        u32x4 au, bu;
        au[0] = packbf2(x0[0], x0[1]); au[1] = packbf2(x0[2], x0[3]);
        au[2] = packbf2(x1[0], x1[1]); au[3] = packbf2(x1[2], x1[3]);
        bu[0] = packbf2(y0[0], y0[1]); bu[1] = packbf2(y0[2], y0[3]);
        bu[2] = packbf2(y1[0], y1[1]); bu[3] = packbf2(y1[2], y1[3]);
        bf16x8 a0, a1;
        __builtin_memcpy(&a0, &au, 16);
        __builtin_memcpy(&a1, &bu, 16);
        #pragma unroll
        for (int nt = 0; nt < 16; ++nt) {
            int frag = kc * 64 + (w * 16 + nt);
            bf16x8 b = *(const bf16x8*)(W1s + frag * 512 + lane * 8);
            acc[0][nt] = __builtin_amdgcn_mfma_f32_16x16x32_bf16(a0, b, acc[0][nt], 0, 0, 0);
            acc[1][nt] = __builtin_amdgcn_mfma_f32_16x16x32_bf16(a1, b, acc[1][nt], 0, 0, 0);
        }
    }

    // C/D layout: col = lane&15, row = (lane>>4)*4 + r.  Fold b1 into the P half (n<512).
    #pragma unroll
    for (int nt = 0; nt < 16; ++nt) {
        int n = w * 256 + nt * 16 + m;
        float bias = (n < 512) ? b1[n] : 0.0f;
        #pragma unroll
        for (int mt = 0; mt < 2; ++mt) {
            #pragma unroll
            for (int r = 0; r < 4; ++r) {
                int node = nb + mt * 16 + kq * 4 + r;
                if (node < N_NODESC)
                    PQ[(size_t)node * 1024 + n] = f2bf(acc[mt][nt][r] + bias);
            }
        }
    }
}

// ============ kernel 2: per-edge fused layer1(gather+add+relu) + layer2(MFMA) + layer3 ============
// grid 3125 x 256: each wave owns 64 edges as 4 m-tiles (R2 structure: best measured).
// 2 waves/SIMD (acc=128 AGPR + ~120 VGPR) -> deep VMEM software-pipelining via full unroll.
// launch_bounds(256,2): do NOT tighten — R4 showed (256,3) strangles prefetch depth.
__global__ __launch_bounds__(256, 2) void edge_kernel(const short* __restrict__ PQ,
                                                      const int* __restrict__ ei,
                                                      const short* __restrict__ W2s,
                                                      const float* __restrict__ b2,
                                                      const float* __restrict__ W3,
                                                      const float* __restrict__ b3,
                                                      float* __restrict__ out) {
    int lane = threadIdx.x & 63;
    int w = threadIdx.x >> 6;
    int e0 = blockIdx.x * 256 + w * 64;
    int m = lane & 15;
    int kq = lane >> 4;

    // 64 col indices in lanes (idx_c), 64 row indices (idx_r); broadcast per tile via shfl
    int idx_c = ei[e0 + lane];
    int idx_r = ei[N_EDGES + e0 + lane];

    const short* pb[4];
    const short* qb[4];
    #pragma unroll
    for (int t = 0; t < 4; ++t) {
        int ce = __shfl(idx_c, t * 16 + m, 64);
        int re = __shfl(idx_r, t * 16 + m, 64);
        pb[t] = PQ + (size_t)ce * 1024 + kq * 8;          // P' half
        qb[t] = PQ + (size_t)re * 1024 + 512 + kq * 8;    // Q half
    }

    f32x4 acc[4][8];
    #pragma unroll
    for (int t = 0; t < 4; ++t)
        #pragma unroll
        for (int nt = 0; nt < 8; ++nt) acc[t][nt] = (f32x4){0.f, 0.f, 0.f, 0.f};

    #pragma unroll
    for (int kc = 0; kc < 16; ++kc) {
        u32x4 p[4], q[4];
        #pragma unroll
        for (int t = 0; t < 4; ++t) {
            p[t] = *(const u32x4*)(pb[t] + kc * 32);
            q[t] = *(const u32x4*)(qb[t] + kc * 32);
        }
        bf16x8 b[8];
        #pragma unroll
        for (int nt = 0; nt < 8; ++nt)
            b[nt] = *(const bf16x8*)(W2s + (kc * 8 + nt) * 512 + lane * 8);
        #pragma unroll
        for (int t = 0; t < 4; ++t) {
            bf16x8 a = addrelu8(p[t], q[t]);
            #pragma unroll
            for (int nt = 0; nt < 8; ++nt)
                acc[t][nt] = __builtin_amdgcn_mfma_f32_16x16x32_bf16(a, b[nt], acc[t][nt], 0, 0, 0);
        }
    }

    // ---- epilogue: +b2, relu, dot with W3, +b3 (all f32) ----
    float b2v[8], w3v[8];
    #pragma unroll
    for (int nt = 0; nt < 8; ++nt) {
        b2v[nt] = b2[nt * 16 + m];
        w3v[nt] = W3[nt * 16 + m];
    }
    float b3s = b3[0];
    #pragma unroll
    for (int t = 0; t < 4; ++t) {
        float partial[4] = {0.f, 0.f, 0.f, 0.f};
        #pragma unroll
        for (int nt = 0; nt < 8; ++nt) {
            #pragma unroll
            for (int r = 0; r < 4; ++r) {
                float x2 = acc[t][nt][r] + b2v[nt];       // C row = kq*4+r, col = nt*16+m
                x2 = x2 > 0.f ? x2 : 0.f;
                partial[r] += x2 * w3v[nt];
            }
        }
        #pragma unroll
        for (int r = 0; r < 4; ++r) {
            #pragma unroll
            for (int off = 1; off < 16; off <<= 1)
                partial[r] += __shfl_xor(partial[r], off, 64);
            if (m == 0) out[e0 + t * 16 + kq * 4 + r] = partial[r] + b3s;
        }
    }
}

extern "C" void kernel_launch(void* const* d_in, const int* in_sizes, int n_in,
                              void* d_out, int out_size, void* d_ws, size_t ws_size,
                              hipStream_t stream) {
    const float* emb = (const float*)d_in[0];
    const int*   ei  = (const int*)d_in[1];
    const float* W1  = (const float*)d_in[2];
    const float* b1  = (const float*)d_in[3];
    const float* W2  = (const float*)d_in[4];
    const float* b2  = (const float*)d_in[5];
    const float* W3  = (const float*)d_in[6];
    const float* b3  = (const float*)d_in[7];
    float* out = (float*)d_out;

    short* PQ  = (short*)((char*)d_ws + PQ_OFF);
    short* W1s = (short*)((char*)d_ws + W1S_OFF);
    short* W2s = (short*)((char*)d_ws + W2S_OFF);

    swizzle_kernel<<<96, 256, 0, stream>>>(W1, W2, W1s, W2s);
    precompute_kernel<<<(N_NODESC + 31) / 32, 256, 0, stream>>>(emb, W1s, b1, PQ);     // 1563 blocks
    edge_kernel<<<N_EDGES / 256, 256, 0, stream>>>(PQ, ei, W2s, b2, W3, b3, out);      // 3125 blocks
}

// Round 6
// 400.277 us; speedup vs baseline: 1.3619x; 1.1879x over previous
//
#include <hip/hip_runtime.h>
#include <hip/hip_bf16.h>
#include <stdint.h>

// Problem constants (fixed by the reference)
#define N_EDGES   800000
#define N_NODESC  50000
#define HID       128

typedef __attribute__((ext_vector_type(8))) short bf16x8;  // 8 bf16 = 4 VGPRs (MFMA A/B frag)
typedef __attribute__((ext_vector_type(4))) float f32x4;   // MFMA C/D frag
typedef __attribute__((ext_vector_type(4))) unsigned int u32x4;

__device__ __forceinline__ short f2bf(float f) {
    union { float f; uint32_t u; } v; v.f = f;
    uint32_t r = v.u + 0x7FFFu + ((v.u >> 16) & 1u);   // round-to-nearest-even
    return (short)(r >> 16);
}

// pack two f32 -> bf16x2 (RNE) via native v_cvt_pk_bf16_f32 on gfx950
__device__ __forceinline__ uint32_t packbf2(float lo, float hi) {
    float2 t; t.x = lo; t.y = hi;
    __hip_bfloat162 h = __float22bfloat162_rn(t);
    uint32_t u;
    __builtin_memcpy(&u, &h, 4);       // __hip_bfloat162 not trivially copyable -> memcpy pun
    return u;
}

// packed bf16x2 (a+b) then relu:
//   __hadd2 -> native v_pk_add_bf16 (one RNE rounding: bf16+bf16 is exact in f32,
//   rounded once — identical error to the f32-add-then-round path)
//   relu: integer sign-mask, exact.  ~5 VALU per 2 elements.
__device__ __forceinline__ uint32_t addrelu2(uint32_t a, uint32_t b) {
    __hip_bfloat162 ha, hb;
    __builtin_memcpy(&ha, &a, 4);
    __builtin_memcpy(&hb, &b, 4);
    __hip_bfloat162 s = __hadd2(ha, hb);
    uint32_t x;
    __builtin_memcpy(&x, &s, 4);
    uint32_t neg = (x & 0x80008000u) >> 15;      // 1 at bit0/bit16 where half negative
    return x & ~(neg * 0xFFFFu);                 // zero negative halves
}
__device__ __forceinline__ bf16x8 addrelu8(u32x4 p, u32x4 q) {
    u32x4 r;
    #pragma unroll
    for (int j = 0; j < 4; ++j) r[j] = addrelu2(p[j], q[j]);
    bf16x8 out;
    __builtin_memcpy(&out, &r, 16);
    return out;
}

// ---------------- workspace layout ----------------
// PQ  : bf16 [50000][1024]  (cols 0..511 = emb@W1_top + b1 "P'", 512..1023 = emb@W1_bot "Q")
// W1s : bf16 frag-major, 4*64 frags x 64 lanes x 8   (B-frags of W1cat [128,1024])
// W2s : bf16 frag-major, 16*8 frags x 64 lanes x 8   (B-frags of W2 [512,128])
#define PQ_OFF   0UL
#define W1S_OFF  102400000UL                 // 50000*1024*2
#define W2S_OFF  (W1S_OFF + 262144UL)        // + 128*1024*2
// total ws needed: 102,793,216 bytes

// ============ kernel 0: weight convert + B-fragment swizzle ============
// B-frag for 16x16x32 bf16: lane l holds B[k = kc*32 + (l>>4)*8 + j][n = nt*16 + (l&15)], j=0..7
__global__ __launch_bounds__(256) void swizzle_kernel(const float* __restrict__ W1,
                                                      const float* __restrict__ W2,
                                                      short* __restrict__ W1s,
                                                      short* __restrict__ W2s) {
    int t = blockIdx.x * 256 + threadIdx.x;
    int lane = t & 63;
    int kq = lane >> 4;       // 0..3
    int nn = lane & 15;
    if (t < 16384) {          // W1cat: K=128, N=1024 -> kc 0..3, nt 0..63
        int frag = t >> 6;
        int kc = frag >> 6;
        int nt = frag & 63;
        int n = nt * 16 + nn;
        int kbase = kc * 32 + kq * 8;
        bf16x8 v;
        #pragma unroll
        for (int j = 0; j < 8; ++j) {
            int k = kbase + j;
            float f = (n < 512) ? W1[k * 512 + n] : W1[(128 + k) * 512 + (n - 512)];
            v[j] = f2bf(f);
        }
        *(bf16x8*)(W1s + frag * 512 + lane * 8) = v;
    } else if (t < 24576) {   // W2: K=512, N=128 -> kc 0..15, nt 0..7
        int t2 = t - 16384;
        int frag = t2 >> 6;
        int kc = frag >> 3;
        int nt = frag & 7;
        int n = nt * 16 + nn;
        int kbase = kc * 32 + kq * 8;
        bf16x8 v;
        #pragma unroll
        for (int j = 0; j < 8; ++j) v[j] = f2bf(W2[(kbase + j) * HID + n]);
        *(bf16x8*)(W2s + frag * 512 + lane * 8) = v;
    }
}

// ============ kernel 1: PQ = emb @ W1cat (+b1 on P half) ============
// grid 3125 x 256: block = 16 node rows (3125*16 = 50000 exactly, no clamps),
// 4 waves each owning a 256-col slice.  acc = 64 AGPR -> ~3 waves/SIMD.
// Key fix vs R5: C-tile goes through a per-wave LDS transpose so PQ stores are
// 8 fully-coalesced dwordx4 (two 512 B segments each) instead of 64 scalar 2 B
// stores (32 B segments, ~4x HBM write inefficiency — the R5 precompute stall).
__global__ __launch_bounds__(256) void precompute_kernel(const float* __restrict__ emb,
                                                         const short* __restrict__ W1s,
                                                         const float* __restrict__ b1,
                                                         short* __restrict__ PQ) {
    // per-wave tile: 16 rows x 256 cols bf16; row stride 272 shorts = 544 B
    // (16 B-aligned for b128 reads; write conflicts <=4-way ~= cheap per m136)
    __shared__ short tile[4][16][272];
    int lane = threadIdx.x & 63;
    int w = threadIdx.x >> 6;
    int nb = blockIdx.x * 16;
    int m = lane & 15;
    int kq = lane >> 4;

    const float* arow = emb + (size_t)(nb + m) * 128 + kq * 8;

    f32x4 acc[16];
    #pragma unroll
    for (int i = 0; i < 16; ++i) acc[i] = (f32x4){0.f, 0.f, 0.f, 0.f};

    #pragma unroll
    for (int kc = 0; kc < 4; ++kc) {
        f32x4 x0 = *(const f32x4*)(arow + kc * 32);
        f32x4 x1 = *(const f32x4*)(arow + kc * 32 + 4);
        u32x4 au;
        au[0] = packbf2(x0[0], x0[1]); au[1] = packbf2(x0[2], x0[3]);
        au[2] = packbf2(x1[0], x1[1]); au[3] = packbf2(x1[2], x1[3]);
        bf16x8 a;
        __builtin_memcpy(&a, &au, 16);
        #pragma unroll
        for (int nt = 0; nt < 16; ++nt) {
            int frag = kc * 64 + (w * 16 + nt);
            bf16x8 b = *(const bf16x8*)(W1s + frag * 512 + lane * 8);
            acc[nt] = __builtin_amdgcn_mfma_f32_16x16x32_bf16(a, b, acc[nt], 0, 0, 0);
        }
    }

    // C/D layout: col = lane&15, row = (lane>>4)*4 + r.  Fold b1 into the P half (n<512).
    // Write C-layout -> LDS (2 B each, wave-private so no barrier needed).
    #pragma unroll
    for (int nt = 0; nt < 16; ++nt) {
        int n = w * 256 + nt * 16 + m;
        float bias = (n < 512) ? b1[n] : 0.0f;
        #pragma unroll
        for (int r = 0; r < 4; ++r)
            tile[w][kq * 4 + r][nt * 16 + m] = f2bf(acc[nt][r] + bias);
    }

    // Read back row-major and store coalesced: lane -> (row = s*2 + lane/32,
    // chunk = lane&31): 16 B per lane, two contiguous 512 B segments per inst.
    #pragma unroll
    for (int s = 0; s < 8; ++s) {
        int row = s * 2 + (lane >> 5);
        int chunk = lane & 31;
        bf16x8 v = *(const bf16x8*)(&tile[w][row][chunk * 8]);
        *(bf16x8*)(PQ + (size_t)(nb + row) * 1024 + w * 256 + chunk * 8) = v;
    }
}

// ============ kernel 2: per-edge fused layer1(gather+add+relu) + layer2(MFMA) + layer3 ============
// grid 3125 x 256: each wave owns 64 edges as 4 m-tiles (R2/R5 structure: best measured).
// 2 waves/SIMD (acc=128 AGPR + ~128 VGPR) -> deep VMEM software-pipelining via full unroll.
// launch_bounds(256,2): do NOT tighten — R4 showed (256,3) strangles prefetch depth.
__global__ __launch_bounds__(256, 2) void edge_kernel(const short* __restrict__ PQ,
                                                      const int* __restrict__ ei,
                                                      const short* __restrict__ W2s,
                                                      const float* __restrict__ b2,
                                                      const float* __restrict__ W3,
                                                      const float* __restrict__ b3,
                                                      float* __restrict__ out) {
    int lane = threadIdx.x & 63;
    int w = threadIdx.x >> 6;
    int e0 = blockIdx.x * 256 + w * 64;
    int m = lane & 15;
    int kq = lane >> 4;

    // 64 col indices in lanes (idx_c), 64 row indices (idx_r); broadcast per tile via shfl
    int idx_c = ei[e0 + lane];
    int idx_r = ei[N_EDGES + e0 + lane];

    const short* pb[4];
    const short* qb[4];
    #pragma unroll
    for (int t = 0; t < 4; ++t) {
        int ce = __shfl(idx_c, t * 16 + m, 64);
        int re = __shfl(idx_r, t * 16 + m, 64);
        pb[t] = PQ + (size_t)ce * 1024 + kq * 8;          // P' half
        qb[t] = PQ + (size_t)re * 1024 + 512 + kq * 8;    // Q half
    }

    f32x4 acc[4][8];
    #pragma unroll
    for (int t = 0; t < 4; ++t)
        #pragma unroll
        for (int nt = 0; nt < 8; ++nt) acc[t][nt] = (f32x4){0.f, 0.f, 0.f, 0.f};

    #pragma unroll
    for (int kc = 0; kc < 16; ++kc) {
        u32x4 p[4], q[4];
        #pragma unroll
        for (int t = 0; t < 4; ++t) {
            p[t] = *(const u32x4*)(pb[t] + kc * 32);
            q[t] = *(const u32x4*)(qb[t] + kc * 32);
        }
        bf16x8 b[8];
        #pragma unroll
        for (int nt = 0; nt < 8; ++nt)
            b[nt] = *(const bf16x8*)(W2s + (kc * 8 + nt) * 512 + lane * 8);
        #pragma unroll
        for (int t = 0; t < 4; ++t) {
            bf16x8 a = addrelu8(p[t], q[t]);
            #pragma unroll
            for (int nt = 0; nt < 8; ++nt)
                acc[t][nt] = __builtin_amdgcn_mfma_f32_16x16x32_bf16(a, b[nt], acc[t][nt], 0, 0, 0);
        }
    }

    // ---- epilogue: +b2, relu, dot with W3, +b3 (all f32) ----
    float b2v[8], w3v[8];
    #pragma unroll
    for (int nt = 0; nt < 8; ++nt) {
        b2v[nt] = b2[nt * 16 + m];
        w3v[nt] = W3[nt * 16 + m];
    }
    float b3s = b3[0];
    #pragma unroll
    for (int t = 0; t < 4; ++t) {
        float partial[4] = {0.f, 0.f, 0.f, 0.f};
        #pragma unroll
        for (int nt = 0; nt < 8; ++nt) {
            #pragma unroll
            for (int r = 0; r < 4; ++r) {
                float x2 = acc[t][nt][r] + b2v[nt];       // C row = kq*4+r, col = nt*16+m
                x2 = x2 > 0.f ? x2 : 0.f;
                partial[r] += x2 * w3v[nt];
            }
        }
        #pragma unroll
        for (int r = 0; r < 4; ++r) {
            #pragma unroll
            for (int off = 1; off < 16; off <<= 1)
                partial[r] += __shfl_xor(partial[r], off, 64);
            if (m == 0) out[e0 + t * 16 + kq * 4 + r] = partial[r] + b3s;
        }
    }
}

extern "C" void kernel_launch(void* const* d_in, const int* in_sizes, int n_in,
                              void* d_out, int out_size, void* d_ws, size_t ws_size,
                              hipStream_t stream) {
    const float* emb = (const float*)d_in[0];
    const int*   ei  = (const int*)d_in[1];
    const float* W1  = (const float*)d_in[2];
    const float* b1  = (const float*)d_in[3];
    const float* W2  = (const float*)d_in[4];
    const float* b2  = (const float*)d_in[5];
    const float* W3  = (const float*)d_in[6];
    const float* b3  = (const float*)d_in[7];
    float* out = (float*)d_out;

    short* PQ  = (short*)((char*)d_ws + PQ_OFF);
    short* W1s = (short*)((char*)d_ws + W1S_OFF);
    short* W2s = (short*)((char*)d_ws + W2S_OFF);

    swizzle_kernel<<<96, 256, 0, stream>>>(W1, W2, W1s, W2s);
    precompute_kernel<<<N_NODESC / 16, 256, 0, stream>>>(emb, W1s, b1, PQ);            // 3125 blocks
    edge_kernel<<<N_EDGES / 256, 256, 0, stream>>>(PQ, ei, W2s, b2, W3, b3, out);      // 3125 blocks
}